// Round 1
// baseline (474.243 us; speedup 1.0000x reference)
//
#include <hip/hip_runtime.h>

#define BB 2
#define NPTS 16384
#define NQ (2*BB*NPTS)        // 65536 query work-items (2 directions x B x N)
#define CHUNKS 8
#define CLEN (NPTS/CHUNKS)    // 2048 candidates per chunk
#define FLT_BIG 3.402823466e+38f

// ws layout:
//   float4 cand[2][BB][NPTS]          : 65536 * 16 B = 1 MB   (dir0: xyz2, dir1: xyz1)
//   float  pd[NQ][CHUNKS]             : 2 MB
//   int    pi[NQ][CHUNKS]             : 2 MB

__global__ __launch_bounds__(256) void prep_kernel(
    const float* __restrict__ xyz1, const float* __restrict__ xyz2,
    float4* __restrict__ cand)
{
    int t = blockIdx.x * 256 + threadIdx.x;   // 0..65535
    int dir = t >> 15;                        // 0: candidates from xyz2, 1: from xyz1
    int rem = t & 32767;                      // b*NPTS + j
    const float* src = dir ? xyz1 : xyz2;
    float x = src[rem*3+0];
    float y = src[rem*3+1];
    float z = src[rem*3+2];
    // match numpy sum(b*b, -1): (x*x + y*y) + z*z, no contraction
    float bsq = __fadd_rn(__fadd_rn(__fmul_rn(x,x), __fmul_rn(y,y)), __fmul_rn(z,z));
    cand[t] = make_float4(x, y, z, bsq);
}

__global__ __launch_bounds__(256) void nn_partial(
    const float* __restrict__ xyz1, const float* __restrict__ xyz2,
    const float4* __restrict__ cand,
    float* __restrict__ pd, int* __restrict__ pi)
{
    int qid = blockIdx.x * 256 + threadIdx.x;   // 0..65535
    int chunk = blockIdx.y;                     // 0..CHUNKS-1
    int dir = qid >> 15;
    int q15 = qid & 32767;                      // b*NPTS + q
    const float* qsrc = dir ? xyz2 : xyz1;      // queries
    float ax = qsrc[q15*3+0];
    float ay = qsrc[q15*3+1];
    float az = qsrc[q15*3+2];
    float asq = __fadd_rn(__fadd_rn(__fmul_rn(ax,ax), __fmul_rn(ay,ay)), __fmul_rn(az,az));

    // candidate base: cand[dir][b][chunk*CLEN ...]
    const float4* cp = cand + (dir << 15) + (q15 & NPTS) + chunk * CLEN;

    float b0 = FLT_BIG, b1 = FLT_BIG, b2 = FLT_BIG, b3 = FLT_BIG;
    int i0 = 0, i1 = 1, i2 = 2, i3 = 3;

    for (int j = 0; j < CLEN; j += 4) {
        float4 c0 = cp[j+0];
        float4 c1 = cp[j+1];
        float4 c2 = cp[j+2];
        float4 c3 = cp[j+3];

        // dot in BLAS k-ascending FMA order: fma(a2,b2, fma(a1,b1, a0*b0))
        float t0 = fmaf(az, c0.z, fmaf(ay, c0.y, __fmul_rn(ax, c0.x)));
        float d0 = fmaf(-2.0f, t0, __fadd_rn(asq, c0.w));  // == (asq+bsq) - 2*dot, single rounding
        if (d0 < b0) { b0 = d0; i0 = j+0; }

        float t1 = fmaf(az, c1.z, fmaf(ay, c1.y, __fmul_rn(ax, c1.x)));
        float d1 = fmaf(-2.0f, t1, __fadd_rn(asq, c1.w));
        if (d1 < b1) { b1 = d1; i1 = j+1; }

        float t2 = fmaf(az, c2.z, fmaf(ay, c2.y, __fmul_rn(ax, c2.x)));
        float d2 = fmaf(-2.0f, t2, __fadd_rn(asq, c2.w));
        if (d2 < b2) { b2 = d2; i2 = j+2; }

        float t3 = fmaf(az, c3.z, fmaf(ay, c3.y, __fmul_rn(ax, c3.x)));
        float d3 = fmaf(-2.0f, t3, __fadd_rn(asq, c3.w));
        if (d3 < b3) { b3 = d3; i3 = j+3; }
    }

    // merge accumulators, ties -> lowest index (jnp.argmin first-occurrence)
    float bd = b0; int bi = i0;
    if (b1 < bd || (b1 == bd && i1 < bi)) { bd = b1; bi = i1; }
    if (b2 < bd || (b2 == bd && i2 < bi)) { bd = b2; bi = i2; }
    if (b3 < bd || (b3 == bd && i3 < bi)) { bd = b3; bi = i3; }

    pd[qid*CHUNKS + chunk] = bd;
    pi[qid*CHUNKS + chunk] = chunk*CLEN + bi;
}

__global__ __launch_bounds__(256) void nn_merge(
    const float* __restrict__ pd, const int* __restrict__ pi,
    float* __restrict__ out)
{
    int qid = blockIdx.x * 256 + threadIdx.x;
    float bd = pd[qid*CHUNKS];
    int   bi = pi[qid*CHUNKS];
    #pragma unroll
    for (int c = 1; c < CHUNKS; ++c) {
        float d = pd[qid*CHUNKS + c];
        int   i = pi[qid*CHUNKS + c];
        if (d < bd || (d == bd && i < bi)) { bd = d; bi = i; }
    }
    int dir = qid >> 15;
    int q15 = qid & 32767;      // b*NPTS + q
    // out: [dist1 (32768) | dist2 (32768) | idx1 (32768) | idx2 (32768)]
    int off = dir ? 32768 : 0;
    out[off + q15]         = bd;
    out[65536 + off + q15] = (float)bi;
}

// Fallback if ws too small: fused, recomputes bsq in-loop.
__global__ __launch_bounds__(256) void nn_full(
    const float* __restrict__ xyz1, const float* __restrict__ xyz2,
    float* __restrict__ out)
{
    int qid = blockIdx.x * 256 + threadIdx.x;
    int dir = qid >> 15;
    int q15 = qid & 32767;
    const float* qsrc = dir ? xyz2 : xyz1;
    float ax = qsrc[q15*3+0];
    float ay = qsrc[q15*3+1];
    float az = qsrc[q15*3+2];
    float asq = __fadd_rn(__fadd_rn(__fmul_rn(ax,ax), __fmul_rn(ay,ay)), __fmul_rn(az,az));
    const float* cp = (dir ? xyz1 : xyz2) + (size_t)(q15 & NPTS) * 3;

    float bd = FLT_BIG; int bi = 0;
    for (int j = 0; j < NPTS; ++j) {
        float bx = cp[3*j+0], by = cp[3*j+1], bz = cp[3*j+2];
        float bsq = __fadd_rn(__fadd_rn(__fmul_rn(bx,bx), __fmul_rn(by,by)), __fmul_rn(bz,bz));
        float t = fmaf(az, bz, fmaf(ay, by, __fmul_rn(ax, bx)));
        float d = fmaf(-2.0f, t, __fadd_rn(asq, bsq));
        if (d < bd) { bd = d; bi = j; }
    }
    int off = dir ? 32768 : 0;
    out[off + q15]         = bd;
    out[65536 + off + q15] = (float)bi;
}

extern "C" void kernel_launch(void* const* d_in, const int* in_sizes, int n_in,
                              void* d_out, int out_size, void* d_ws, size_t ws_size,
                              hipStream_t stream) {
    const float* xyz1 = (const float*)d_in[0];
    const float* xyz2 = (const float*)d_in[1];
    float* out = (float*)d_out;

    size_t cand_bytes = (size_t)NQ * 16;                 // 1 MB
    size_t pd_bytes   = (size_t)NQ * CHUNKS * 4;         // 2 MB
    size_t need = cand_bytes + 2 * pd_bytes;             // 5 MB

    if (d_ws != nullptr && ws_size >= need) {
        float4* cand = (float4*)d_ws;
        float*  pd   = (float*)((char*)d_ws + cand_bytes);
        int*    pi   = (int*)((char*)d_ws + cand_bytes + pd_bytes);
        prep_kernel<<<NQ/256, 256, 0, stream>>>(xyz1, xyz2, cand);
        dim3 grid(NQ/256, CHUNKS);
        nn_partial<<<grid, 256, 0, stream>>>(xyz1, xyz2, cand, pd, pi);
        nn_merge<<<NQ/256, 256, 0, stream>>>(pd, pi, out);
    } else {
        nn_full<<<NQ/256, 256, 0, stream>>>(xyz1, xyz2, out);
    }
}

// Round 2
// 247.719 us; speedup vs baseline: 1.9144x; 1.9144x over previous
//
#include <hip/hip_runtime.h>

#define BB 2
#define NPTS 16384
#define NQ (2*BB*NPTS)        // 65536 query work-items (2 directions x B x N)
#define FLT_BIG 3.402823466e+38f

// ws layout (CH = CHUNKS):
//   float4 cand[2][BB][NPTS]   : 1 MB  (slot 0: xyz2 points, slot 1: xyz1 points)
//   float  pd[CH][NQ]          : CH*256 KB
//   int    pi[CH][NQ]          : CH*256 KB

__global__ __launch_bounds__(256) void prep_kernel(
    const float* __restrict__ xyz1, const float* __restrict__ xyz2,
    float4* __restrict__ cand)
{
    int t = blockIdx.x * 256 + threadIdx.x;   // 0..65535
    int dir = t >> 15;                        // 0: xyz2 points, 1: xyz1 points
    int rem = t & 32767;                      // b*NPTS + j
    const float* src = dir ? xyz1 : xyz2;
    float x = src[rem*3+0];
    float y = src[rem*3+1];
    float z = src[rem*3+2];
    // match numpy sum(b*b, -1): (x*x + y*y) + z*z, no contraction
    float sq = __fadd_rn(__fadd_rn(__fmul_rn(x,x), __fmul_rn(y,y)), __fmul_rn(z,z));
    cand[t] = make_float4(x, y, z, sq);
}

// 4 queries per thread; candidate loads are block-uniform and amortized x4.
// Grid: (64, CH). Block bx covers 1024 consecutive qids; blockIdx.y = candidate chunk.
template<int CH>
__global__ __launch_bounds__(256) void nn_partial4(
    const float4* __restrict__ cand,
    float* __restrict__ pd, int* __restrict__ pi)
{
    constexpr int CLEN = NPTS / CH;
    const int bx    = blockIdx.x;          // 0..63
    const int chunk = blockIdx.y;          // 0..CH-1
    const int dir   = bx >> 5;             // 32 blocks per direction
    const int q15b  = (bx & 31) << 10;     // within-direction base (b*NPTS + q), 1024-aligned
    const int bb    = (q15b >> 14) & 1;    // batch index

    const float4* qt = cand + ((dir ^ 1) << 15) + q15b;                  // queries
    const float4* cp = cand + (dir << 15) + (bb << 14) + chunk * CLEN;   // candidates

    const int lane = threadIdx.x & 63;
    const int w    = threadIdx.x >> 6;
    const int qoff = w * 256 + lane;       // this thread's queries: qoff + k*64, k=0..3

    float ax[4], ay[4], az[4], aw[4];
    #pragma unroll
    for (int k = 0; k < 4; ++k) {
        float4 qv = qt[qoff + k*64];
        ax[k] = qv.x; ay[k] = qv.y; az[k] = qv.z; aw[k] = qv.w;
    }

    float bd[4]; int bi[4];
    #pragma unroll
    for (int k = 0; k < 4; ++k) { bd[k] = FLT_BIG; bi[k] = 0; }

    for (int j = 0; j < CLEN; j += 2) {
        float4 c0 = cp[j];
        float4 c1 = cp[j+1];
        #pragma unroll
        for (int k = 0; k < 4; ++k) {
            // dot in BLAS k-ascending FMA order, then single-rounded (asq+bsq) - 2*dot
            float t0 = fmaf(az[k], c0.z, fmaf(ay[k], c0.y, __fmul_rn(ax[k], c0.x)));
            float d0 = fmaf(-2.0f, t0, __fadd_rn(aw[k], c0.w));
            if (d0 < bd[k]) { bd[k] = d0; bi[k] = j; }
            float t1 = fmaf(az[k], c1.z, fmaf(ay[k], c1.y, __fmul_rn(ax[k], c1.x)));
            float d1 = fmaf(-2.0f, t1, __fadd_rn(aw[k], c1.w));
            if (d1 < bd[k]) { bd[k] = d1; bi[k] = j+1; }
        }
    }

    const int qid0 = (dir << 15) + q15b + qoff;
    #pragma unroll
    for (int k = 0; k < 4; ++k) {
        int qid = qid0 + k*64;
        pd[chunk*NQ + qid] = bd[k];
        pi[chunk*NQ + qid] = chunk*CLEN + bi[k];
    }
}

template<int CH>
__global__ __launch_bounds__(256) void nn_merge(
    const float* __restrict__ pd, const int* __restrict__ pi,
    float* __restrict__ out)
{
    int qid = blockIdx.x * 256 + threadIdx.x;
    float bd = pd[qid];
    int   bi = pi[qid];
    #pragma unroll
    for (int c = 1; c < CH; ++c) {
        float d = pd[c*NQ + qid];
        int   i = pi[c*NQ + qid];
        if (d < bd || (d == bd && i < bi)) { bd = d; bi = i; }  // lower index wins ties
    }
    int dir = qid >> 15;
    int q15 = qid & 32767;
    // out: [dist1 (32768) | dist2 (32768) | idx1 (32768) | idx2 (32768)]
    int off = dir ? 32768 : 0;
    out[off + q15]         = bd;
    out[65536 + off + q15] = (float)bi;
}

// Ultimate fallback (no ws): fused, recomputes bsq in-loop.
__global__ __launch_bounds__(256) void nn_full(
    const float* __restrict__ xyz1, const float* __restrict__ xyz2,
    float* __restrict__ out)
{
    int qid = blockIdx.x * 256 + threadIdx.x;
    int dir = qid >> 15;
    int q15 = qid & 32767;
    const float* qsrc = dir ? xyz2 : xyz1;
    float ax = qsrc[q15*3+0];
    float ay = qsrc[q15*3+1];
    float az = qsrc[q15*3+2];
    float asq = __fadd_rn(__fadd_rn(__fmul_rn(ax,ax), __fmul_rn(ay,ay)), __fmul_rn(az,az));
    const float* cp = (dir ? xyz1 : xyz2) + (size_t)(q15 & NPTS) * 3;

    float bd = FLT_BIG; int bi = 0;
    for (int j = 0; j < NPTS; ++j) {
        float bx = cp[3*j+0], by = cp[3*j+1], bz = cp[3*j+2];
        float bsq = __fadd_rn(__fadd_rn(__fmul_rn(bx,bx), __fmul_rn(by,by)), __fmul_rn(bz,bz));
        float t = fmaf(az, bz, fmaf(ay, by, __fmul_rn(ax, bx)));
        float d = fmaf(-2.0f, t, __fadd_rn(asq, bsq));
        if (d < bd) { bd = d; bi = j; }
    }
    int off = dir ? 32768 : 0;
    out[off + q15]         = bd;
    out[65536 + off + q15] = (float)bi;
}

extern "C" void kernel_launch(void* const* d_in, const int* in_sizes, int n_in,
                              void* d_out, int out_size, void* d_ws, size_t ws_size,
                              hipStream_t stream) {
    const float* xyz1 = (const float*)d_in[0];
    const float* xyz2 = (const float*)d_in[1];
    float* out = (float*)d_out;

    size_t cand_bytes = (size_t)NQ * 16;  // 1 MB

    auto run = [&](auto ch_const) {
        constexpr int CH = decltype(ch_const)::value;
        float4* cand = (float4*)d_ws;
        float*  pd   = (float*)((char*)d_ws + cand_bytes);
        int*    pi   = (int*)((char*)d_ws + cand_bytes + (size_t)CH*NQ*4);
        prep_kernel<<<NQ/256, 256, 0, stream>>>(xyz1, xyz2, cand);
        dim3 grid(64, CH);
        nn_partial4<CH><<<grid, 256, 0, stream>>>(cand, pd, pi);
        nn_merge<CH><<<NQ/256, 256, 0, stream>>>(pd, pi, out);
    };

    size_t need32 = cand_bytes + (size_t)32*NQ*8;  // 17 MB
    size_t need8  = cand_bytes + (size_t)8*NQ*8;   // 5 MB
    if (d_ws != nullptr && ws_size >= need32) {
        run(std::integral_constant<int, 32>{});
    } else if (d_ws != nullptr && ws_size >= need8) {
        run(std::integral_constant<int, 8>{});
    } else {
        nn_full<<<NQ/256, 256, 0, stream>>>(xyz1, xyz2, out);
    }
}